// Round 3
// baseline (373.872 us; speedup 1.0000x reference)
//
#include <hip/hip_runtime.h>

// CORDIV stochastic-computing divider — Round 3: MLP-batched loads,
// native clang vector type so __builtin_nontemporal_store compiles.
//
// R1 post-mortem: 133us @ 2.1 TB/s, VGPR=32 -> compiler serialized
// load->waitcnt->compute->store per t (only ~2 outstanding loads/wave).
// Fix: two phases of 8 t-steps; each phase issues 16 float4 loads
// back-to-back into a register array before any use (~16 outstanding
// 1KB requests per wave), then computes + nontemporal-stores 8 planes.
// Output is write-once -> nt stores avoid polluting L2/L3 so inputs
// stay cached (harness restore leaves them warm in Infinity Cache).

#define SC_T   16
#define SC_BUF 4
#define PHASE  8   // t-steps per load batch

typedef float v4f __attribute__((ext_vector_type(4)));

__global__ __launch_bounds__(256) void cordiv_kernel(
    const v4f* __restrict__ dividend,
    const v4f* __restrict__ divisor,
    const v4f* __restrict__ sr_init,
    const int* __restrict__ rng_table,
    v4f*       __restrict__ out,
    int n4)   // N / 4
{
    const int gid = blockIdx.x * blockDim.x + threadIdx.x;
    if (gid >= n4) return;

    // rng table values (uniform address -> scalar loads; uniform per t)
    const int r0 = rng_table[0];
    const int r1 = rng_table[1];
    const int r2 = rng_table[2];
    const int r3 = rng_table[3];
    const int rtab[SC_BUF] = {r0, r1, r2, r3};

    v4f sr0 = sr_init[0 * n4 + gid];
    v4f sr1 = sr_init[1 * n4 + gid];
    v4f sr2 = sr_init[2 * n4 + gid];
    v4f sr3 = sr_init[3 * n4 + gid];

    v4f dvd[PHASE], dvs[PHASE];

#pragma unroll
    for (int p = 0; p < SC_T / PHASE; ++p) {
        const int tbase = p * PHASE;

        // Phase load: 16 independent 16B loads issued back-to-back.
#pragma unroll
        for (int i = 0; i < PHASE; ++i) {
            dvd[i] = dividend[(tbase + i) * n4 + gid];
            dvs[i] = divisor [(tbase + i) * n4 + gid];
        }

        // Phase compute + store.
#pragma unroll
        for (int i = 0; i < PHASE; ++i) {
            const int t = tbase + i;
            const int r = rtab[t & (SC_BUF - 1)];   // constant-folded per t

            const v4f hq = (r == 0) ? sr0 : (r == 1) ? sr1
                         : (r == 2) ? sr2 : sr3;

            v4f q;
            q.x = (dvs[i].x == 1.0f) ? dvd[i].x : hq.x;
            q.y = (dvs[i].y == 1.0f) ? dvd[i].y : hq.y;
            q.z = (dvs[i].z == 1.0f) ? dvd[i].z : hq.z;
            q.w = (dvs[i].w == 1.0f) ? dvd[i].w : hq.w;

            __builtin_nontemporal_store(q, &out[t * n4 + gid]);

            sr3 = sr2; sr2 = sr1; sr1 = sr0; sr0 = q;
        }
    }
}

extern "C" void kernel_launch(void* const* d_in, const int* in_sizes, int n_in,
                              void* d_out, int out_size, void* d_ws, size_t ws_size,
                              hipStream_t stream) {
    const float* dividend = (const float*)d_in[0];   // [T, N]
    const float* divisor  = (const float*)d_in[1];   // [T, N]
    const float* sr_init  = (const float*)d_in[2];   // [BUF_DEP, N]
    const int*   rng      = (const int*)d_in[3];     // [4]
    float*       out      = (float*)d_out;           // [T, N]

    const int n  = in_sizes[0] / SC_T;   // N
    const int n4 = n / 4;                // N = 2^21, divisible by 4

    const int block = 256;
    const int grid  = (n4 + block - 1) / block;

    cordiv_kernel<<<grid, block, 0, stream>>>(
        (const v4f*)dividend, (const v4f*)divisor,
        (const v4f*)sr_init, rng, (v4f*)out, n4);
}

// Round 4
// 351.396 us; speedup vs baseline: 1.0640x; 1.0640x over previous
//
#include <hip/hip_runtime.h>

// CORDIV stochastic-computing divider — Round 4: force-hoisted load batches.
//
// R3 post-mortem: VGPR=60 proves the compiler sank the 16-load batch back to
// per-iteration load->wait->store (reg-pressure heuristic), and nt stores
// lengthened the vmcnt drain (HBM ack instead of L2). 133us = ~620 cyc/iter
// = one memory round-trip per iteration, zero cross-iteration MLP.
//
// Fix:
//  - __launch_bounds__(256, 4): VGPR budget 128/wave, stops pressure-sinking.
//  - __builtin_amdgcn_sched_barrier(0) after each load batch: sinking illegal.
//  - PHASE=4 -> 8 outstanding 1KB loads/wave (8KB); ~4 waves/SIMD -> ~128KB
//    outstanding/CU, enough to cover ~600cyc loaded latency at HBM rate.
//  - plain (allocating) stores: fast L2 ack on the shared vmcnt counter.

#define SC_T   16
#define SC_BUF 4
#define PHASE  4   // t-steps per load batch (8 loads in flight)

typedef float v4f __attribute__((ext_vector_type(4)));

__global__ __launch_bounds__(256, 4) void cordiv_kernel(
    const v4f* __restrict__ dividend,
    const v4f* __restrict__ divisor,
    const v4f* __restrict__ sr_init,
    const int* __restrict__ rng_table,
    v4f*       __restrict__ out,
    int n4)   // N / 4
{
    const int gid = blockIdx.x * blockDim.x + threadIdx.x;
    if (gid >= n4) return;

    // rng table values (uniform address -> scalar loads; uniform per t)
    const int r0 = rng_table[0];
    const int r1 = rng_table[1];
    const int r2 = rng_table[2];
    const int r3 = rng_table[3];
    const int rtab[SC_BUF] = {r0, r1, r2, r3};

    v4f sr0 = sr_init[0 * n4 + gid];
    v4f sr1 = sr_init[1 * n4 + gid];
    v4f sr2 = sr_init[2 * n4 + gid];
    v4f sr3 = sr_init[3 * n4 + gid];

    v4f dvd[PHASE], dvs[PHASE];

#pragma unroll
    for (int p = 0; p < SC_T / PHASE; ++p) {
        const int tbase = p * PHASE;

        // Load batch: 8 independent 16B loads issued back-to-back.
#pragma unroll
        for (int i = 0; i < PHASE; ++i) {
            dvd[i] = dividend[(tbase + i) * n4 + gid];
            dvs[i] = divisor [(tbase + i) * n4 + gid];
        }

        // Nothing may cross: loads above stay above (cannot be sunk into
        // the compute loop), guaranteeing 8 requests in flight.
        __builtin_amdgcn_sched_barrier(0);

        // Compute + store.
#pragma unroll
        for (int i = 0; i < PHASE; ++i) {
            const int t = tbase + i;
            const int r = rtab[t & (SC_BUF - 1)];   // constant-folded per t

            const v4f hq = (r == 0) ? sr0 : (r == 1) ? sr1
                         : (r == 2) ? sr2 : sr3;

            v4f q;
            q.x = (dvs[i].x == 1.0f) ? dvd[i].x : hq.x;
            q.y = (dvs[i].y == 1.0f) ? dvd[i].y : hq.y;
            q.z = (dvs[i].z == 1.0f) ? dvd[i].z : hq.z;
            q.w = (dvs[i].w == 1.0f) ? dvd[i].w : hq.w;

            out[t * n4 + gid] = q;

            sr3 = sr2; sr2 = sr1; sr1 = sr0; sr0 = q;
        }
    }
}

extern "C" void kernel_launch(void* const* d_in, const int* in_sizes, int n_in,
                              void* d_out, int out_size, void* d_ws, size_t ws_size,
                              hipStream_t stream) {
    const float* dividend = (const float*)d_in[0];   // [T, N]
    const float* divisor  = (const float*)d_in[1];   // [T, N]
    const float* sr_init  = (const float*)d_in[2];   // [BUF_DEP, N]
    const int*   rng      = (const int*)d_in[3];     // [4]
    float*       out      = (float*)d_out;           // [T, N]

    const int n  = in_sizes[0] / SC_T;   // N
    const int n4 = n / 4;                // N = 2^21, divisible by 4

    const int block = 256;
    const int grid  = (n4 + block - 1) / block;

    cordiv_kernel<<<grid, block, 0, stream>>>(
        (const v4f*)dividend, (const v4f*)divisor,
        (const v4f*)sr_init, rng, (v4f*)out, n4);
}

// Round 5
// 336.268 us; speedup vs baseline: 1.1118x; 1.0450x over previous
//
#include <hip/hip_runtime.h>

// CORDIV stochastic-computing divider — Round 5: register-tie pinned batches.
//
// R4 post-mortem: sched_barrier(0) + launch_bounds(256,4) left VGPR=32 and
// 133us — the load batch was sunk at IR level before the machine scheduler
// ever saw the barrier. Loads-to-registers get rematerialized next to uses
// whenever only scheduling hints oppose it.
//
// Fix: DATA-dependence pinning. Each phase does 8 plain loads, then an empty
// `asm volatile` that ties all 8 loaded values as "+v" operands:
//   - loads cannot sink below it (asm consumes their results),
//   - consumers cannot hoist above it (asm redefines the values),
//   - compiler emits ONE s_waitcnt for the whole batch -> 8 loads in flight.
// Cost: zero instructions. VGPR rises to ~56 (32 data + 16 sr + addr).
// Per wave: 4 memory round-trips total instead of 16.

#define SC_T   16
#define SC_BUF 4
#define PHASE  4   // t-steps per pinned batch (8 loads in flight)

typedef float v4f __attribute__((ext_vector_type(4)));

__global__ __launch_bounds__(256) void cordiv_kernel(
    const v4f* __restrict__ dividend,
    const v4f* __restrict__ divisor,
    const v4f* __restrict__ sr_init,
    const int* __restrict__ rng_table,
    v4f*       __restrict__ out,
    int n4)   // N / 4
{
    const int gid = blockIdx.x * blockDim.x + threadIdx.x;
    if (gid >= n4) return;

    // rng table values (uniform address -> scalar loads; uniform per t)
    const int r0 = rng_table[0];
    const int r1 = rng_table[1];
    const int r2 = rng_table[2];
    const int r3 = rng_table[3];
    const int rtab[SC_BUF] = {r0, r1, r2, r3};

    v4f sr0 = sr_init[0 * n4 + gid];
    v4f sr1 = sr_init[1 * n4 + gid];
    v4f sr2 = sr_init[2 * n4 + gid];
    v4f sr3 = sr_init[3 * n4 + gid];

#pragma unroll
    for (int p = 0; p < SC_T / PHASE; ++p) {
        const int tbase = p * PHASE;

        v4f dvd[PHASE], dvs[PHASE];

        // 8 independent 16B loads, issued back-to-back.
#pragma unroll
        for (int i = 0; i < PHASE; ++i) {
            dvd[i] = dividend[(tbase + i) * n4 + gid];
            dvs[i] = divisor [(tbase + i) * n4 + gid];
        }

        // Data-dependence pin: all 8 values must be materialized here.
        asm volatile(""
            : "+v"(dvd[0]), "+v"(dvd[1]), "+v"(dvd[2]), "+v"(dvd[3]),
              "+v"(dvs[0]), "+v"(dvs[1]), "+v"(dvs[2]), "+v"(dvs[3]));

        // Compute + store.
#pragma unroll
        for (int i = 0; i < PHASE; ++i) {
            const int t = tbase + i;
            const int r = rtab[t & (SC_BUF - 1)];   // constant-folded per t

            const v4f hq = (r == 0) ? sr0 : (r == 1) ? sr1
                         : (r == 2) ? sr2 : sr3;

            v4f q;
            q.x = (dvs[i].x == 1.0f) ? dvd[i].x : hq.x;
            q.y = (dvs[i].y == 1.0f) ? dvd[i].y : hq.y;
            q.z = (dvs[i].z == 1.0f) ? dvd[i].z : hq.z;
            q.w = (dvs[i].w == 1.0f) ? dvd[i].w : hq.w;

            out[t * n4 + gid] = q;

            sr3 = sr2; sr2 = sr1; sr1 = sr0; sr0 = q;
        }
    }
}

extern "C" void kernel_launch(void* const* d_in, const int* in_sizes, int n_in,
                              void* d_out, int out_size, void* d_ws, size_t ws_size,
                              hipStream_t stream) {
    const float* dividend = (const float*)d_in[0];   // [T, N]
    const float* divisor  = (const float*)d_in[1];   // [T, N]
    const float* sr_init  = (const float*)d_in[2];   // [BUF_DEP, N]
    const int*   rng      = (const int*)d_in[3];     // [4]
    float*       out      = (float*)d_out;           // [T, N]

    const int n  = in_sizes[0] / SC_T;   // N
    const int n4 = n / 4;                // N = 2^21, divisible by 4

    const int block = 256;
    const int grid  = (n4 + block - 1) / block;

    cordiv_kernel<<<grid, block, 0, stream>>>(
        (const v4f*)dividend, (const v4f*)divisor,
        (const v4f*)sr_init, rng, (v4f*)out, n4);
}